// Round 20
// baseline (213.561 us; speedup 1.0000x reference)
//
#include <hip/hip_runtime.h>
#include <hip/hip_fp16.h>
#include <math.h>

#define N_NODES 50000
#define N_EDGES 800000
#define NGRAPH  1024
#define IN_DIM  25
#define DIM     64

// CSR binning: coarse buckets of 512 dst nodes; fill by 8 sub-blocks of 64.
#define NBK 98                     // coarse buckets = ceil(N/512)
#define CAP 12288                  // edges cap per coarse bucket (mean 8192)
#define NPB 64                     // nodes per fill sub-block
#define NFILL (NBK * 8)            // fill blocks
#define NBIN 782                   // ceil(N_EDGES / 1024) edge-binning blocks
#define CROWS 128                  // set2set LDS row cache (mean 49, max ~80)

__device__ inline float wsum(float v) {
#pragma unroll
  for (int off = 32; off > 0; off >>= 1) v += __shfl_xor(v, off, 64);
  return v;
}
__device__ inline int wsumi(int v) {
#pragma unroll
  for (int off = 32; off > 0; off >>= 1) v += __shfl_xor(v, off, 64);
  return v;
}
__device__ inline float sigmoidf(float x) { return 1.f / (1.f + expf(-x)); }

// ---- bin edges: LDS counting-sort per block -> coalesced bucket runs -----
// sorted entry: (bkt << 25) | (col_local << 16) | row ; pairs keeps low 25b.
__global__ __launch_bounds__(256) void k_bin(const int* __restrict__ ei,
    int* __restrict__ gcur, int* __restrict__ pairs,
    const float* __restrict__ Wih, const float* __restrict__ Whh,
    __half* __restrict__ WTh) {
  __shared__ int hist[NBK];
  __shared__ int sbase[NBK];
  __shared__ int lbase[NBK];
  __shared__ int sorted[1024];
  int t = threadIdx.x;
  if (blockIdx.x == NBIN) {  // ---- LSTM weight transpose (fp16): WTh[k][gate]
    for (int i = t; i < 3 * DIM * 4 * DIM; i += 256) {
      int k = i >> 8, tt = i & 255;
      float v = (k < 2 * DIM) ? Wih[tt * 2 * DIM + k] : Whh[tt * DIM + (k - 2 * DIM)];
      WTh[i] = __float2half(v);
    }
    return;
  }
  int base = blockIdx.x * 1024;
  for (int i = t; i < NBK; i += 256) hist[i] = 0;
  __syncthreads();
  int pk[4], bkt[4], rank[4];
#pragma unroll
  for (int k = 0; k < 4; k++) {
    int e = base + k * 256 + t;
    if (e < N_EDGES) {
      int row = ei[e];
      int col = ei[N_EDGES + e];
      int b = col >> 9;
      bkt[k] = b;
      rank[k] = atomicAdd(&hist[b], 1);
      pk[k] = (b << 25) | ((col & 511) << 16) | row;
    } else {
      bkt[k] = -1;
    }
  }
  __syncthreads();
  // exclusive scan of hist (wave 0: 2 entries/lane covers 128 >= 98)
  if (t < 64) {
    int i0 = 2 * t, i1 = 2 * t + 1;
    int v0 = (i0 < NBK) ? hist[i0] : 0;
    int v1 = (i1 < NBK) ? hist[i1] : 0;
    int loc = v0 + v1, x = loc;
#pragma unroll
    for (int d = 1; d < 64; d <<= 1) {
      int y = __shfl_up(x, d, 64);
      if (t >= d) x += y;
    }
    int excl = x - loc;
    if (i0 < NBK) sbase[i0] = excl;
    if (i1 < NBK) sbase[i1] = excl + v0;
  }
  __syncthreads();
#pragma unroll
  for (int k = 0; k < 4; k++)
    if (bkt[k] >= 0) sorted[sbase[bkt[k]] + rank[k]] = pk[k];
  for (int i = t; i < NBK; i += 256)
    lbase[i] = hist[i] ? atomicAdd(&gcur[i], hist[i]) : 0;
  __syncthreads();
  int ntot = min(1024, N_EDGES - base);
  for (int i = t; i < ntot; i += 256) {
    int p = sorted[i];
    int b = ((unsigned)p) >> 25;
    int gpos = lbase[b] + (i - sbase[b]);
    if (gpos < CAP) pairs[(size_t)b * CAP + gpos] = p & 0x1FFFFFF;
  }
}

// ---- CSR fill: 8 sub-blocks per coarse bucket; int4-vectorized passes ----
__global__ __launch_bounds__(256) void k_fillcsr(const int* __restrict__ pairs,
    const int* __restrict__ gcur, int* __restrict__ cnt,
    float* __restrict__ dinv, int* __restrict__ adj) {
  __shared__ int hist[NPB];
  __shared__ int sbase, sbef;
  int b = blockIdx.x;
  int cb = b >> 3, sub = b & 7;
  int t = threadIdx.x, lane = t & 63;
  int lo = sub * NPB;           // local col range [lo, lo+NPB)
  int nb0 = cb * 512 + lo;      // first node of this sub-block
  if (t < NPB) hist[t] = 0;
  if (t == 0) { sbef = 0; sbase = 0; }
  __syncthreads();
  int ne = min(gcur[cb], CAP);
  const int* pp = pairs + (size_t)cb * CAP;
  const int4* pp4 = (const int4*)pp;
  int ne4 = ne >> 2;
  int mybef = 0;
  for (int i = t; i < ne4; i += 256) {
    int4 p4 = pp4[i];
    int c0 = p4.x >> 16, c1 = p4.y >> 16, c2 = p4.z >> 16, c3 = p4.w >> 16;
    if ((unsigned)(c0 - lo) < NPB) atomicAdd(&hist[c0 - lo], 1);
    if ((unsigned)(c1 - lo) < NPB) atomicAdd(&hist[c1 - lo], 1);
    if ((unsigned)(c2 - lo) < NPB) atomicAdd(&hist[c2 - lo], 1);
    if ((unsigned)(c3 - lo) < NPB) atomicAdd(&hist[c3 - lo], 1);
    mybef += (c0 < lo) + (c1 < lo) + (c2 < lo) + (c3 < lo);
  }
  for (int i = (ne4 << 2) + t; i < ne; i += 256) {
    int c = pp[i] >> 16;
    if ((unsigned)(c - lo) < NPB) atomicAdd(&hist[c - lo], 1);
    mybef += (c < lo);
  }
  mybef = wsumi(mybef);
  if (lane == 0 && mybef) atomicAdd(&sbef, mybef);
  __syncthreads();
  // dinv from raw counts (+1 self loop)
  if (t < NPB) {
    int node = nb0 + t;
    if (node < N_NODES) dinv[node] = rsqrtf((float)(hist[t] + 1));
  }
  // coarse-bucket base = sum of gcur[j] for j < cb (wave 0)
  if (t < 64) {
    int v = 0;
    for (int i = t; i < cb; i += 64) v += gcur[i];
    v = wsumi(v);
    if (t == 0) sbase = v;
  }
  __syncthreads();
  int basev = sbase + sbef;
  // exclusive scan of hist in place, absolute offsets (wave 0: 1 per lane)
  if (t < 64) {
    int v0 = hist[t];
    int x = v0;
#pragma unroll
    for (int d = 1; d < 64; d <<= 1) {
      int y = __shfl_up(x, d, 64);
      if (t >= d) x += y;
    }
    hist[t] = basev + x - v0;
  }
  __syncthreads();
  // write absolute CSR offsets
  if (t < NPB) {
    int node = nb0 + t;
    if (node < N_NODES) cnt[node] = hist[t];
  }
  if (b == NFILL - 1 && t == 0) cnt[N_NODES] = N_EDGES;  // sentinel
  __syncthreads();
  // fill adj via LDS cursors (absolute slots), int4 reads
  for (int i = t; i < ne4; i += 256) {
    int4 p4 = pp4[i];
#pragma unroll
    for (int u = 0; u < 4; u++) {
      int p = (&p4.x)[u];
      unsigned cl = (unsigned)((p >> 16) - lo);
      if (cl < NPB) {
        int slot = atomicAdd(&hist[cl], 1);
        adj[slot] = p & 0xFFFF;
      }
    }
  }
  for (int i = (ne4 << 2) + t; i < ne; i += 256) {
    int p = pp[i];
    unsigned cl = (unsigned)((p >> 16) - lo);
    if (cl < NPB) {
      int slot = atomicAdd(&hist[cl], 1);
      adj[slot] = p & 0xFFFF;
    }
  }
}

// ---- lin0 + relu + @Wc: LDS-tiled GEMM; stores hw16 = dinv[row]*result ---
__global__ __launch_bounds__(256) void k_lin0(const float* __restrict__ x,
    const float* __restrict__ W0, const float* __restrict__ b0,
    const float* __restrict__ Wc, const float* __restrict__ dinv,
    __half* __restrict__ hw16) {
  __shared__ float sx[64][IN_DIM + 1];
  __shared__ float sW0[IN_DIM][DIM];
  __shared__ float sh[64][DIM + 4];
  __shared__ float sWc[DIM][DIM];
  int t = threadIdx.x;
  int row0 = blockIdx.x * 64;
  for (int i = t; i < 64 * IN_DIM; i += 256) {
    int r = i / IN_DIM, k = i - r * IN_DIM;
    int row = row0 + r;
    sx[r][k] = (row < N_NODES) ? x[row * IN_DIM + k] : 0.f;
  }
  for (int i = t; i < IN_DIM * DIM; i += 256) sW0[i >> 6][i & 63] = W0[i];
  for (int i = t; i < DIM * DIM; i += 256) sWc[i >> 6][i & 63] = Wc[i];
  __syncthreads();
  int tc = (t & 15) * 4;
  int tr = (t >> 4) * 4;
  float acc[4][4];
  {
    float4 bb = *(const float4*)&b0[tc];
#pragma unroll
    for (int i = 0; i < 4; i++) {
      acc[i][0] = bb.x; acc[i][1] = bb.y; acc[i][2] = bb.z; acc[i][3] = bb.w;
    }
  }
#pragma unroll
  for (int k = 0; k < IN_DIM; k++) {
    float4 w = *(const float4*)&sW0[k][tc];
#pragma unroll
    for (int i = 0; i < 4; i++) {
      float a = sx[tr + i][k];
      acc[i][0] += a * w.x; acc[i][1] += a * w.y;
      acc[i][2] += a * w.z; acc[i][3] += a * w.w;
    }
  }
#pragma unroll
  for (int i = 0; i < 4; i++) {
    sh[tr + i][tc + 0] = fmaxf(acc[i][0], 0.f);
    sh[tr + i][tc + 1] = fmaxf(acc[i][1], 0.f);
    sh[tr + i][tc + 2] = fmaxf(acc[i][2], 0.f);
    sh[tr + i][tc + 3] = fmaxf(acc[i][3], 0.f);
  }
  __syncthreads();
#pragma unroll
  for (int i = 0; i < 4; i++) acc[i][0] = acc[i][1] = acc[i][2] = acc[i][3] = 0.f;
#pragma unroll 8
  for (int k = 0; k < DIM; k++) {
    float4 w = *(const float4*)&sWc[k][tc];
#pragma unroll
    for (int i = 0; i < 4; i++) {
      float a = sh[tr + i][k];
      acc[i][0] += a * w.x; acc[i][1] += a * w.y;
      acc[i][2] += a * w.z; acc[i][3] += a * w.w;
    }
  }
  float2* hwf2 = (float2*)hw16;
#pragma unroll
  for (int i = 0; i < 4; i++) {
    int row = row0 + tr + i;
    if (row < N_NODES) {
      float dv = dinv[row];
      float2 st;
      ((__half2*)&st)[0] = __floats2half2_rn(acc[i][0] * dv, acc[i][1] * dv);
      ((__half2*)&st)[1] = __floats2half2_rn(acc[i][2] * dv, acc[i][3] * dv);
      hwf2[(size_t)row * 16 + (t & 15)] = st;
    }
  }
}

// ---- GCN aggregate: quarter-wave per node, adj prefetch, fp16 in/out -----
__global__ __launch_bounds__(256) void k_gather(const int* __restrict__ adj,
    const int* __restrict__ cnt, const __half* __restrict__ hw16,
    const float* __restrict__ dinv, const float4* __restrict__ bc4,
    __half* __restrict__ h16) {
  int t = threadIdx.x;
  int lane = t & 63, wave = t >> 6;
  int q = lane >> 4, ql = lane & 15;
  int node = blockIdx.x * 16 + wave * 4 + q;
  if (node >= N_NODES) return;
  const float2* hwf2 = (const float2*)hw16;
  int s = cnt[node], eend = cnt[node + 1];
  float di = dinv[node];
  float4 a0 = make_float4(0.f, 0.f, 0.f, 0.f), a1 = a0, a2 = a0, a3 = a0;
  {  // self loop (already di-scaled)
    float2 raw = hwf2[(size_t)node * 16 + ql];
    float2 f0 = __half22float2(((const __half2*)&raw)[0]);
    float2 f1 = __half22float2(((const __half2*)&raw)[1]);
    a0.x = f0.x; a0.y = f0.y; a0.z = f1.x; a0.w = f1.y;
  }
  int qb = q << 4;
  int idx = 0;
  if (s < eend && ql < eend - s) idx = adj[s + ql];
  for (int cb = s; cb < eend; cb += 16) {
    int cn = min(16, eend - cb);
    int nb = cb + 16;
    int nidx = 0;  // prefetch next chunk's indices before consuming current
    if (nb < eend && ql < eend - nb) nidx = adj[nb + ql];
    int j = 0;
    for (; j + 4 <= cn; j += 4) {
      int r0 = __shfl(idx, qb + j, 64), r1 = __shfl(idx, qb + j + 1, 64);
      int r2 = __shfl(idx, qb + j + 2, 64), r3 = __shfl(idx, qb + j + 3, 64);
      float2 w0 = hwf2[(size_t)r0 * 16 + ql];
      float2 w1 = hwf2[(size_t)r1 * 16 + ql];
      float2 w2 = hwf2[(size_t)r2 * 16 + ql];
      float2 w3 = hwf2[(size_t)r3 * 16 + ql];
      float2 f;
      f = __half22float2(((const __half2*)&w0)[0]); a0.x += f.x; a0.y += f.y;
      f = __half22float2(((const __half2*)&w0)[1]); a0.z += f.x; a0.w += f.y;
      f = __half22float2(((const __half2*)&w1)[0]); a1.x += f.x; a1.y += f.y;
      f = __half22float2(((const __half2*)&w1)[1]); a1.z += f.x; a1.w += f.y;
      f = __half22float2(((const __half2*)&w2)[0]); a2.x += f.x; a2.y += f.y;
      f = __half22float2(((const __half2*)&w2)[1]); a2.z += f.x; a2.w += f.y;
      f = __half22float2(((const __half2*)&w3)[0]); a3.x += f.x; a3.y += f.y;
      f = __half22float2(((const __half2*)&w3)[1]); a3.z += f.x; a3.w += f.y;
    }
    for (; j < cn; j++) {
      int r = __shfl(idx, qb + j, 64);
      float2 w = hwf2[(size_t)r * 16 + ql];
      float2 f;
      f = __half22float2(((const __half2*)&w)[0]); a0.x += f.x; a0.y += f.y;
      f = __half22float2(((const __half2*)&w)[1]); a0.z += f.x; a0.w += f.y;
    }
    idx = nidx;
  }
  float4 bb = bc4[ql];
  float ox = fmaxf(((a0.x + a1.x) + (a2.x + a3.x)) * di + bb.x, 0.f);
  float oy = fmaxf(((a0.y + a1.y) + (a2.y + a3.y)) * di + bb.y, 0.f);
  float oz = fmaxf(((a0.z + a1.z) + (a2.z + a3.z)) * di + bb.z, 0.f);
  float ow = fmaxf(((a0.w + a1.w) + (a2.w + a3.w)) * di + bb.w, 0.f);
  float2 st;
  ((__half2*)&st)[0] = __floats2half2_rn(ox, oy);
  ((__half2*)&st)[1] = __floats2half2_rn(oz, ow);
  ((float2*)h16)[(size_t)node * 16 + ql] = st;
}

// ---- fused Set2Set: LDS row cache reused across 3 attention passes -------
__global__ __launch_bounds__(256) void k_set2set(
    const __half* __restrict__ h16, const int* __restrict__ batch,
    const __half* __restrict__ WTh, const float* __restrict__ bih,
    const float* __restrict__ bhh, const float* __restrict__ W1,
    const float* __restrict__ b1, const float* __restrict__ W2,
    const float* __restrict__ b2, float* __restrict__ out) {
  int b = blockIdx.x, t = threadIdx.x;
  int wave = t >> 6, lane = t & 63;
  int q = lane >> 4, ql = lane & 15;
  int qid = (wave << 2) + q;  // 0..15
  __shared__ float2 hcf2[CROWS * 16];  // 16 KiB fp16 row cache
  __shared__ float qs[2 * DIM];
  __shared__ float hsl[DIM], csl[DIM];
  __shared__ float gates[4 * DIM];
  __shared__ float red[16 * DIM];
  __shared__ float lred[16], wmax[16];
  __shared__ int seg[2];
  const float2* h2 = (const float2*)h16;
  if (t < 2) {  // graph boundary via binary search on sorted batch
    int g = b + t;
    int lo = 0, hi = N_NODES;
    if (g == NGRAPH) lo = N_NODES;
    else while (lo < hi) { int mid = (lo + hi) >> 1; if (batch[mid] < g) lo = mid + 1; else hi = mid; }
    seg[t] = lo;
  }
  if (t < 2 * DIM) qs[t] = 0.f;
  if (t < DIM) { hsl[t] = 0.f; csl[t] = 0.f; }
  __syncthreads();
  int s = seg[0], eend = seg[1];
  int nc = min(eend - s, CROWS);
  for (int i = t; i < nc * 16; i += 256)
    hcf2[i] = h2[(size_t)(s + (i >> 4)) * 16 + (i & 15)];
  __syncthreads();
  float bsum = bih[t] + bhh[t];
  for (int step = 0; step < 3; step++) {
    // ---- LSTM cell: thread t computes gate t (coalesced WTh reads) ----
    float g = bsum;
    if (step > 0) {  // step 0: q_star = hs = 0 -> matmul contributes nothing
      const __half* wp = WTh + t;
      float g0 = 0.f, g1 = 0.f, g2 = 0.f, g3 = 0.f;
#pragma unroll 8
      for (int k = 0; k < 2 * DIM; k += 4) {
        g0 += qs[k] * __half2float(wp[k * 4 * DIM]);
        g1 += qs[k + 1] * __half2float(wp[(k + 1) * 4 * DIM]);
        g2 += qs[k + 2] * __half2float(wp[(k + 2) * 4 * DIM]);
        g3 += qs[k + 3] * __half2float(wp[(k + 3) * 4 * DIM]);
      }
#pragma unroll 8
      for (int k = 0; k < DIM; k += 4) {
        g0 += hsl[k] * __half2float(wp[(2 * DIM + k) * 4 * DIM]);
        g1 += hsl[k + 1] * __half2float(wp[(2 * DIM + k + 1) * 4 * DIM]);
        g2 += hsl[k + 2] * __half2float(wp[(2 * DIM + k + 2) * 4 * DIM]);
        g3 += hsl[k + 3] * __half2float(wp[(2 * DIM + k + 3) * 4 * DIM]);
      }
      g += (g0 + g1) + (g2 + g3);
    }
    gates[t] = g;
    __syncthreads();
    if (t < DIM) {
      float ig = sigmoidf(gates[t]);
      float fg = sigmoidf(gates[DIM + t]);
      float gg = tanhf(gates[2 * DIM + t]);
      float og = sigmoidf(gates[3 * DIM + t]);
      float c = fg * csl[t] + ig * gg;
      csl[t] = c;
      float hh = og * tanhf(c);
      hsl[t] = hh;
      qs[t] = hh;  // q half of q_star
    }
    __syncthreads();
    // ---- quarter-wave online softmax over LDS-cached rows ----
    float4 qf = *(const float4*)&hsl[4 * ql];
    float m_w = -INFINITY, l_w = 0.f;
    float4 racc = make_float4(0.f, 0.f, 0.f, 0.f);
    for (int j = s + qid; j < eend; j += 16) {
      int lj = j - s;
      float2 raw = (lj < CROWS) ? hcf2[lj * 16 + ql]
                                : h2[(size_t)j * 16 + ql];
      float2 f0 = __half22float2(((const __half2*)&raw)[0]);
      float2 f1 = __half22float2(((const __half2*)&raw)[1]);
      float p = f0.x * qf.x + f0.y * qf.y + f1.x * qf.z + f1.y * qf.w;
#pragma unroll
      for (int off = 1; off < 16; off <<= 1) p += __shfl_xor(p, off, 64);
      float m_new = fmaxf(m_w, p);
      float scale = __expf(m_w - m_new);  // first row: exp(-inf)=0
      float a = __expf(p - m_new);
      racc.x = racc.x * scale + a * f0.x;
      racc.y = racc.y * scale + a * f0.y;
      racc.z = racc.z * scale + a * f1.x;
      racc.w = racc.w * scale + a * f1.y;
      l_w = l_w * scale + a;
      m_w = m_new;
    }
    *(float4*)&red[qid * DIM + 4 * ql] = racc;
    if (ql == 0) { lred[qid] = l_w; wmax[qid] = m_w; }
    __syncthreads();
    if (t < DIM) {
      float m_b = -1e30f;  // floor avoids NaN for empty graphs
      for (int i = 0; i < 16; i++) m_b = fmaxf(m_b, wmax[i]);
      float r = 0.f, l = 0.f;
      for (int i = 0; i < 16; i++) {
        float e = __expf(wmax[i] - m_b);
        r += red[i * DIM + t] * e;
        l += lred[i] * e;
      }
      qs[DIM + t] = (l > 0.f) ? r / l : 0.f;
    }
    __syncthreads();
  }
  // ---- output MLP head ----
  if (t < DIM) {
    float acc = b1[t];
#pragma unroll
    for (int k = 0; k < 2 * DIM; k++) acc += qs[k] * W1[k * DIM + t];
    acc = fmaxf(acc, 0.f);
    float v = wsum(acc * W2[t]);
    if (t == 0) out[b] = v + b2[0];
  }
}

extern "C" void kernel_launch(void* const* d_in, const int* in_sizes, int n_in,
                              void* d_out, int out_size, void* d_ws, size_t ws_size,
                              hipStream_t stream) {
  const float* x    = (const float*)d_in[0];
  const int*   ei   = (const int*)d_in[1];
  const int*   batch= (const int*)d_in[2];
  const float* W0   = (const float*)d_in[3];
  const float* b0   = (const float*)d_in[4];
  const float* Wc   = (const float*)d_in[5];
  const float* bc   = (const float*)d_in[6];
  const float* Wih  = (const float*)d_in[7];
  const float* Whh  = (const float*)d_in[8];
  const float* bih  = (const float*)d_in[9];
  const float* bhh  = (const float*)d_in[10];
  const float* W1   = (const float*)d_in[11];
  const float* b1   = (const float*)d_in[12];
  const float* W2   = (const float*)d_in[13];
  const float* b2   = (const float*)d_in[14];
  float* out = (float*)d_out;

  __half* hw16 = (__half*)d_ws;                      // N*DIM halves (6.4 MB)
  __half* h16  = hw16 + (size_t)N_NODES * DIM;       // N*DIM halves (6.4 MB)
  float* dinv  = (float*)(h16 + (size_t)N_NODES * DIM);  // N
  __half* WTh  = (__half*)(dinv + N_NODES);          // 192*256 halves (96 KB)
  int* cnt     = (int*)(WTh + 3 * DIM * 4 * DIM);    // N+4 (offsets + sentinel)
  int* adj     = cnt + N_NODES + 4;                  // N_EDGES
  int* gcur    = adj + N_EDGES;                      // NBK bucket counters (+pad)
  int* pairs   = gcur + NBK + 2;                     // NBK*CAP packed edges (16B-aligned)

  hipMemsetAsync(gcur, 0, NBK * sizeof(int), stream);
  k_bin<<<NBIN + 1, 256, 0, stream>>>(ei, gcur, pairs, Wih, Whh, WTh);
  k_fillcsr<<<NFILL, 256, 0, stream>>>(pairs, gcur, cnt, dinv, adj);
  k_lin0<<<(N_NODES + 63) / 64, 256, 0, stream>>>(x, W0, b0, Wc, dinv, hw16);
  k_gather<<<(N_NODES + 15) / 16, 256, 0, stream>>>(adj, cnt, hw16, dinv,
                                                    (const float4*)bc, h16);
  k_set2set<<<NGRAPH, 256, 0, stream>>>(h16, batch, WTh, bih, bhh, W1, b1, W2, b2, out);
}

// Round 21
// 201.373 us; speedup vs baseline: 1.0605x; 1.0605x over previous
//
#include <hip/hip_runtime.h>
#include <hip/hip_fp16.h>
#include <math.h>

#define N_NODES 50000
#define N_EDGES 800000
#define NGRAPH  1024
#define IN_DIM  25
#define DIM     64

// CSR binning: coarse buckets of 512 dst nodes; fill by 8 sub-blocks of 64.
#define NBK 98                     // coarse buckets = ceil(N/512)
#define CAP 12288                  // edges cap per coarse bucket (mean 8192)
#define NPB 64                     // nodes per fill sub-block
#define NFILL (NBK * 8)            // fill blocks
#define NBIN 391                   // ceil(N_EDGES / 2048) edge-binning blocks
#define CROWS 128                  // set2set LDS row cache (mean 49, max ~80)

__device__ inline float wsum(float v) {
#pragma unroll
  for (int off = 32; off > 0; off >>= 1) v += __shfl_xor(v, off, 64);
  return v;
}
__device__ inline int wsumi(int v) {
#pragma unroll
  for (int off = 32; off > 0; off >>= 1) v += __shfl_xor(v, off, 64);
  return v;
}
__device__ inline float sigmoidf(float x) { return 1.f / (1.f + expf(-x)); }

// ---- bin edges: LDS counting-sort per block -> coalesced bucket runs -----
// sorted entry: (bkt << 25) | (col_local << 16) | row ; pairs keeps low 25b.
__global__ __launch_bounds__(256) void k_bin(const int* __restrict__ ei,
    int* __restrict__ gcur, int* __restrict__ pairs,
    const float* __restrict__ Wih, const float* __restrict__ Whh,
    __half* __restrict__ WTh) {
  __shared__ int hist[NBK];
  __shared__ int sbase[NBK];
  __shared__ int lbase[NBK];
  __shared__ int sorted[2048];
  int t = threadIdx.x;
  if (blockIdx.x == NBIN) {  // ---- LSTM weight transpose (fp16): WTh[k][gate]
    for (int i = t; i < 3 * DIM * 4 * DIM; i += 256) {
      int k = i >> 8, tt = i & 255;
      float v = (k < 2 * DIM) ? Wih[tt * 2 * DIM + k] : Whh[tt * DIM + (k - 2 * DIM)];
      WTh[i] = __float2half(v);
    }
    return;
  }
  int base = blockIdx.x * 2048;
  for (int i = t; i < NBK; i += 256) hist[i] = 0;
  __syncthreads();
  int pk[8], bkt[8], rank[8];
#pragma unroll
  for (int k = 0; k < 8; k++) {
    int e = base + k * 256 + t;
    if (e < N_EDGES) {
      int row = ei[e];
      int col = ei[N_EDGES + e];
      int b = col >> 9;
      bkt[k] = b;
      rank[k] = atomicAdd(&hist[b], 1);
      pk[k] = (b << 25) | ((col & 511) << 16) | row;
    } else {
      bkt[k] = -1;
    }
  }
  __syncthreads();
  // exclusive scan of hist (wave 0: 2 entries/lane covers 128 >= 98)
  if (t < 64) {
    int i0 = 2 * t, i1 = 2 * t + 1;
    int v0 = (i0 < NBK) ? hist[i0] : 0;
    int v1 = (i1 < NBK) ? hist[i1] : 0;
    int loc = v0 + v1, x = loc;
#pragma unroll
    for (int d = 1; d < 64; d <<= 1) {
      int y = __shfl_up(x, d, 64);
      if (t >= d) x += y;
    }
    int excl = x - loc;
    if (i0 < NBK) sbase[i0] = excl;
    if (i1 < NBK) sbase[i1] = excl + v0;
  }
  __syncthreads();
#pragma unroll
  for (int k = 0; k < 8; k++)
    if (bkt[k] >= 0) sorted[sbase[bkt[k]] + rank[k]] = pk[k];
  for (int i = t; i < NBK; i += 256)
    lbase[i] = hist[i] ? atomicAdd(&gcur[i], hist[i]) : 0;
  __syncthreads();
  int ntot = min(2048, N_EDGES - base);
  for (int i = t; i < ntot; i += 256) {
    int p = sorted[i];
    int b = ((unsigned)p) >> 25;
    int gpos = lbase[b] + (i - sbase[b]);
    if (gpos < CAP) pairs[(size_t)b * CAP + gpos] = p & 0x1FFFFFF;
  }
}

// ---- CSR fill: 8 sub-blocks per coarse bucket; int4-vectorized passes ----
__global__ __launch_bounds__(256) void k_fillcsr(const int* __restrict__ pairs,
    const int* __restrict__ gcur, int* __restrict__ cnt,
    float* __restrict__ dinv, int* __restrict__ adj) {
  __shared__ int hist[NPB];
  __shared__ int sbase, sbef;
  int b = blockIdx.x;
  int cb = b >> 3, sub = b & 7;
  int t = threadIdx.x, lane = t & 63;
  int lo = sub * NPB;           // local col range [lo, lo+NPB)
  int nb0 = cb * 512 + lo;      // first node of this sub-block
  if (t < NPB) hist[t] = 0;
  if (t == 0) { sbef = 0; sbase = 0; }
  __syncthreads();
  int ne = min(gcur[cb], CAP);
  const int* pp = pairs + (size_t)cb * CAP;
  const int4* pp4 = (const int4*)pp;
  int ne4 = ne >> 2;
  int mybef = 0;
  for (int i = t; i < ne4; i += 256) {
    int4 p4 = pp4[i];
    int c0 = p4.x >> 16, c1 = p4.y >> 16, c2 = p4.z >> 16, c3 = p4.w >> 16;
    if ((unsigned)(c0 - lo) < NPB) atomicAdd(&hist[c0 - lo], 1);
    if ((unsigned)(c1 - lo) < NPB) atomicAdd(&hist[c1 - lo], 1);
    if ((unsigned)(c2 - lo) < NPB) atomicAdd(&hist[c2 - lo], 1);
    if ((unsigned)(c3 - lo) < NPB) atomicAdd(&hist[c3 - lo], 1);
    mybef += (c0 < lo) + (c1 < lo) + (c2 < lo) + (c3 < lo);
  }
  for (int i = (ne4 << 2) + t; i < ne; i += 256) {
    int c = pp[i] >> 16;
    if ((unsigned)(c - lo) < NPB) atomicAdd(&hist[c - lo], 1);
    mybef += (c < lo);
  }
  mybef = wsumi(mybef);
  if (lane == 0 && mybef) atomicAdd(&sbef, mybef);
  __syncthreads();
  // dinv from raw counts (+1 self loop)
  if (t < NPB) {
    int node = nb0 + t;
    if (node < N_NODES) dinv[node] = rsqrtf((float)(hist[t] + 1));
  }
  // coarse-bucket base = sum of gcur[j] for j < cb (wave 0)
  if (t < 64) {
    int v = 0;
    for (int i = t; i < cb; i += 64) v += gcur[i];
    v = wsumi(v);
    if (t == 0) sbase = v;
  }
  __syncthreads();
  int basev = sbase + sbef;
  // exclusive scan of hist in place, absolute offsets (wave 0: 1 per lane)
  if (t < 64) {
    int v0 = hist[t];
    int x = v0;
#pragma unroll
    for (int d = 1; d < 64; d <<= 1) {
      int y = __shfl_up(x, d, 64);
      if (t >= d) x += y;
    }
    hist[t] = basev + x - v0;
  }
  __syncthreads();
  // write absolute CSR offsets
  if (t < NPB) {
    int node = nb0 + t;
    if (node < N_NODES) cnt[node] = hist[t];
  }
  if (b == NFILL - 1 && t == 0) cnt[N_NODES] = N_EDGES;  // sentinel
  __syncthreads();
  // fill adj via LDS cursors (absolute slots), int4 reads
  for (int i = t; i < ne4; i += 256) {
    int4 p4 = pp4[i];
#pragma unroll
    for (int u = 0; u < 4; u++) {
      int p = (&p4.x)[u];
      unsigned cl = (unsigned)((p >> 16) - lo);
      if (cl < NPB) {
        int slot = atomicAdd(&hist[cl], 1);
        adj[slot] = p & 0xFFFF;
      }
    }
  }
  for (int i = (ne4 << 2) + t; i < ne; i += 256) {
    int p = pp[i];
    unsigned cl = (unsigned)((p >> 16) - lo);
    if (cl < NPB) {
      int slot = atomicAdd(&hist[cl], 1);
      adj[slot] = p & 0xFFFF;
    }
  }
}

// ---- lin0 + relu + @Wc: LDS-tiled GEMM; stores hw16 = dinv[row]*result ---
__global__ __launch_bounds__(256) void k_lin0(const float* __restrict__ x,
    const float* __restrict__ W0, const float* __restrict__ b0,
    const float* __restrict__ Wc, const float* __restrict__ dinv,
    __half* __restrict__ hw16) {
  __shared__ float sx[64][IN_DIM + 1];
  __shared__ float sW0[IN_DIM][DIM];
  __shared__ float sh[64][DIM + 4];
  __shared__ float sWc[DIM][DIM];
  int t = threadIdx.x;
  int row0 = blockIdx.x * 64;
  for (int i = t; i < 64 * IN_DIM; i += 256) {
    int r = i / IN_DIM, k = i - r * IN_DIM;
    int row = row0 + r;
    sx[r][k] = (row < N_NODES) ? x[row * IN_DIM + k] : 0.f;
  }
  for (int i = t; i < IN_DIM * DIM; i += 256) sW0[i >> 6][i & 63] = W0[i];
  for (int i = t; i < DIM * DIM; i += 256) sWc[i >> 6][i & 63] = Wc[i];
  __syncthreads();
  int tc = (t & 15) * 4;
  int tr = (t >> 4) * 4;
  float acc[4][4];
  {
    float4 bb = *(const float4*)&b0[tc];
#pragma unroll
    for (int i = 0; i < 4; i++) {
      acc[i][0] = bb.x; acc[i][1] = bb.y; acc[i][2] = bb.z; acc[i][3] = bb.w;
    }
  }
#pragma unroll
  for (int k = 0; k < IN_DIM; k++) {
    float4 w = *(const float4*)&sW0[k][tc];
#pragma unroll
    for (int i = 0; i < 4; i++) {
      float a = sx[tr + i][k];
      acc[i][0] += a * w.x; acc[i][1] += a * w.y;
      acc[i][2] += a * w.z; acc[i][3] += a * w.w;
    }
  }
#pragma unroll
  for (int i = 0; i < 4; i++) {
    sh[tr + i][tc + 0] = fmaxf(acc[i][0], 0.f);
    sh[tr + i][tc + 1] = fmaxf(acc[i][1], 0.f);
    sh[tr + i][tc + 2] = fmaxf(acc[i][2], 0.f);
    sh[tr + i][tc + 3] = fmaxf(acc[i][3], 0.f);
  }
  __syncthreads();
#pragma unroll
  for (int i = 0; i < 4; i++) acc[i][0] = acc[i][1] = acc[i][2] = acc[i][3] = 0.f;
#pragma unroll 8
  for (int k = 0; k < DIM; k++) {
    float4 w = *(const float4*)&sWc[k][tc];
#pragma unroll
    for (int i = 0; i < 4; i++) {
      float a = sh[tr + i][k];
      acc[i][0] += a * w.x; acc[i][1] += a * w.y;
      acc[i][2] += a * w.z; acc[i][3] += a * w.w;
    }
  }
  float2* hwf2 = (float2*)hw16;
#pragma unroll
  for (int i = 0; i < 4; i++) {
    int row = row0 + tr + i;
    if (row < N_NODES) {
      float dv = dinv[row];
      float2 st;
      ((__half2*)&st)[0] = __floats2half2_rn(acc[i][0] * dv, acc[i][1] * dv);
      ((__half2*)&st)[1] = __floats2half2_rn(acc[i][2] * dv, acc[i][3] * dv);
      hwf2[(size_t)row * 16 + (t & 15)] = st;
    }
  }
}

// ---- GCN aggregate: quarter-wave per node, adj prefetch, fp16 in/out -----
__global__ __launch_bounds__(256) void k_gather(const int* __restrict__ adj,
    const int* __restrict__ cnt, const __half* __restrict__ hw16,
    const float* __restrict__ dinv, const float4* __restrict__ bc4,
    __half* __restrict__ h16) {
  int t = threadIdx.x;
  int lane = t & 63, wave = t >> 6;
  int q = lane >> 4, ql = lane & 15;
  int node = blockIdx.x * 16 + wave * 4 + q;
  if (node >= N_NODES) return;
  const float2* hwf2 = (const float2*)hw16;
  int s = cnt[node], eend = cnt[node + 1];
  float di = dinv[node];
  float4 a0 = make_float4(0.f, 0.f, 0.f, 0.f), a1 = a0, a2 = a0, a3 = a0;
  {  // self loop (already di-scaled)
    float2 raw = hwf2[(size_t)node * 16 + ql];
    float2 f0 = __half22float2(((const __half2*)&raw)[0]);
    float2 f1 = __half22float2(((const __half2*)&raw)[1]);
    a0.x = f0.x; a0.y = f0.y; a0.z = f1.x; a0.w = f1.y;
  }
  int qb = q << 4;
  int idx = 0;
  if (s < eend && ql < eend - s) idx = adj[s + ql];
  for (int cb = s; cb < eend; cb += 16) {
    int cn = min(16, eend - cb);
    int nb = cb + 16;
    int nidx = 0;  // prefetch next chunk's indices before consuming current
    if (nb < eend && ql < eend - nb) nidx = adj[nb + ql];
    int j = 0;
    for (; j + 4 <= cn; j += 4) {
      int r0 = __shfl(idx, qb + j, 64), r1 = __shfl(idx, qb + j + 1, 64);
      int r2 = __shfl(idx, qb + j + 2, 64), r3 = __shfl(idx, qb + j + 3, 64);
      float2 w0 = hwf2[(size_t)r0 * 16 + ql];
      float2 w1 = hwf2[(size_t)r1 * 16 + ql];
      float2 w2 = hwf2[(size_t)r2 * 16 + ql];
      float2 w3 = hwf2[(size_t)r3 * 16 + ql];
      float2 f;
      f = __half22float2(((const __half2*)&w0)[0]); a0.x += f.x; a0.y += f.y;
      f = __half22float2(((const __half2*)&w0)[1]); a0.z += f.x; a0.w += f.y;
      f = __half22float2(((const __half2*)&w1)[0]); a1.x += f.x; a1.y += f.y;
      f = __half22float2(((const __half2*)&w1)[1]); a1.z += f.x; a1.w += f.y;
      f = __half22float2(((const __half2*)&w2)[0]); a2.x += f.x; a2.y += f.y;
      f = __half22float2(((const __half2*)&w2)[1]); a2.z += f.x; a2.w += f.y;
      f = __half22float2(((const __half2*)&w3)[0]); a3.x += f.x; a3.y += f.y;
      f = __half22float2(((const __half2*)&w3)[1]); a3.z += f.x; a3.w += f.y;
    }
    for (; j < cn; j++) {
      int r = __shfl(idx, qb + j, 64);
      float2 w = hwf2[(size_t)r * 16 + ql];
      float2 f;
      f = __half22float2(((const __half2*)&w)[0]); a0.x += f.x; a0.y += f.y;
      f = __half22float2(((const __half2*)&w)[1]); a0.z += f.x; a0.w += f.y;
    }
    idx = nidx;
  }
  float4 bb = bc4[ql];
  float ox = fmaxf(((a0.x + a1.x) + (a2.x + a3.x)) * di + bb.x, 0.f);
  float oy = fmaxf(((a0.y + a1.y) + (a2.y + a3.y)) * di + bb.y, 0.f);
  float oz = fmaxf(((a0.z + a1.z) + (a2.z + a3.z)) * di + bb.z, 0.f);
  float ow = fmaxf(((a0.w + a1.w) + (a2.w + a3.w)) * di + bb.w, 0.f);
  float2 st;
  ((__half2*)&st)[0] = __floats2half2_rn(ox, oy);
  ((__half2*)&st)[1] = __floats2half2_rn(oz, ow);
  ((float2*)h16)[(size_t)node * 16 + ql] = st;
}

// ---- fused Set2Set: LDS row cache reused across 3 attention passes -------
__global__ __launch_bounds__(256) void k_set2set(
    const __half* __restrict__ h16, const int* __restrict__ batch,
    const __half* __restrict__ WTh, const float* __restrict__ bih,
    const float* __restrict__ bhh, const float* __restrict__ W1,
    const float* __restrict__ b1, const float* __restrict__ W2,
    const float* __restrict__ b2, float* __restrict__ out) {
  int b = blockIdx.x, t = threadIdx.x;
  int wave = t >> 6, lane = t & 63;
  int q = lane >> 4, ql = lane & 15;
  int qid = (wave << 2) + q;  // 0..15
  __shared__ float2 hcf2[CROWS * 16];  // 16 KiB fp16 row cache
  __shared__ float qs[2 * DIM];
  __shared__ float hsl[DIM], csl[DIM];
  __shared__ float gates[4 * DIM];
  __shared__ float red[16 * DIM];
  __shared__ float lred[16], wmax[16];
  __shared__ int seg[2];
  const float2* h2 = (const float2*)h16;
  if (t < 2) {  // graph boundary via binary search on sorted batch
    int g = b + t;
    int lo = 0, hi = N_NODES;
    if (g == NGRAPH) lo = N_NODES;
    else while (lo < hi) { int mid = (lo + hi) >> 1; if (batch[mid] < g) lo = mid + 1; else hi = mid; }
    seg[t] = lo;
  }
  if (t < 2 * DIM) qs[t] = 0.f;
  if (t < DIM) { hsl[t] = 0.f; csl[t] = 0.f; }
  __syncthreads();
  int s = seg[0], eend = seg[1];
  int nc = min(eend - s, CROWS);
  for (int i = t; i < nc * 16; i += 256)
    hcf2[i] = h2[(size_t)(s + (i >> 4)) * 16 + (i & 15)];
  __syncthreads();
  float bsum = bih[t] + bhh[t];
  for (int step = 0; step < 3; step++) {
    // ---- LSTM cell: thread t computes gate t (coalesced WTh reads) ----
    float g = bsum;
    if (step > 0) {  // step 0: q_star = hs = 0 -> matmul contributes nothing
      const __half* wp = WTh + t;
      float g0 = 0.f, g1 = 0.f, g2 = 0.f, g3 = 0.f;
#pragma unroll 8
      for (int k = 0; k < 2 * DIM; k += 4) {
        g0 += qs[k] * __half2float(wp[k * 4 * DIM]);
        g1 += qs[k + 1] * __half2float(wp[(k + 1) * 4 * DIM]);
        g2 += qs[k + 2] * __half2float(wp[(k + 2) * 4 * DIM]);
        g3 += qs[k + 3] * __half2float(wp[(k + 3) * 4 * DIM]);
      }
#pragma unroll 8
      for (int k = 0; k < DIM; k += 4) {
        g0 += hsl[k] * __half2float(wp[(2 * DIM + k) * 4 * DIM]);
        g1 += hsl[k + 1] * __half2float(wp[(2 * DIM + k + 1) * 4 * DIM]);
        g2 += hsl[k + 2] * __half2float(wp[(2 * DIM + k + 2) * 4 * DIM]);
        g3 += hsl[k + 3] * __half2float(wp[(2 * DIM + k + 3) * 4 * DIM]);
      }
      g += (g0 + g1) + (g2 + g3);
    }
    gates[t] = g;
    __syncthreads();
    if (t < DIM) {
      float ig = sigmoidf(gates[t]);
      float fg = sigmoidf(gates[DIM + t]);
      float gg = tanhf(gates[2 * DIM + t]);
      float og = sigmoidf(gates[3 * DIM + t]);
      float c = fg * csl[t] + ig * gg;
      csl[t] = c;
      float hh = og * tanhf(c);
      hsl[t] = hh;
      qs[t] = hh;  // q half of q_star
    }
    __syncthreads();
    // ---- quarter-wave online softmax over LDS-cached rows ----
    float4 qf = *(const float4*)&hsl[4 * ql];
    float m_w = -INFINITY, l_w = 0.f;
    float4 racc = make_float4(0.f, 0.f, 0.f, 0.f);
    for (int j = s + qid; j < eend; j += 16) {
      int lj = j - s;
      float2 raw = (lj < CROWS) ? hcf2[lj * 16 + ql]
                                : h2[(size_t)j * 16 + ql];
      float2 f0 = __half22float2(((const __half2*)&raw)[0]);
      float2 f1 = __half22float2(((const __half2*)&raw)[1]);
      float p = f0.x * qf.x + f0.y * qf.y + f1.x * qf.z + f1.y * qf.w;
#pragma unroll
      for (int off = 1; off < 16; off <<= 1) p += __shfl_xor(p, off, 64);
      float m_new = fmaxf(m_w, p);
      float scale = __expf(m_w - m_new);  // first row: exp(-inf)=0
      float a = __expf(p - m_new);
      racc.x = racc.x * scale + a * f0.x;
      racc.y = racc.y * scale + a * f0.y;
      racc.z = racc.z * scale + a * f1.x;
      racc.w = racc.w * scale + a * f1.y;
      l_w = l_w * scale + a;
      m_w = m_new;
    }
    *(float4*)&red[qid * DIM + 4 * ql] = racc;
    if (ql == 0) { lred[qid] = l_w; wmax[qid] = m_w; }
    __syncthreads();
    if (t < DIM) {
      float m_b = -1e30f;  // floor avoids NaN for empty graphs
      for (int i = 0; i < 16; i++) m_b = fmaxf(m_b, wmax[i]);
      float r = 0.f, l = 0.f;
      for (int i = 0; i < 16; i++) {
        float e = __expf(wmax[i] - m_b);
        r += red[i * DIM + t] * e;
        l += lred[i] * e;
      }
      qs[DIM + t] = (l > 0.f) ? r / l : 0.f;
    }
    __syncthreads();
  }
  // ---- output MLP head ----
  if (t < DIM) {
    float acc = b1[t];
#pragma unroll
    for (int k = 0; k < 2 * DIM; k++) acc += qs[k] * W1[k * DIM + t];
    acc = fmaxf(acc, 0.f);
    float v = wsum(acc * W2[t]);
    if (t == 0) out[b] = v + b2[0];
  }
}

extern "C" void kernel_launch(void* const* d_in, const int* in_sizes, int n_in,
                              void* d_out, int out_size, void* d_ws, size_t ws_size,
                              hipStream_t stream) {
  const float* x    = (const float*)d_in[0];
  const int*   ei   = (const int*)d_in[1];
  const int*   batch= (const int*)d_in[2];
  const float* W0   = (const float*)d_in[3];
  const float* b0   = (const float*)d_in[4];
  const float* Wc   = (const float*)d_in[5];
  const float* bc   = (const float*)d_in[6];
  const float* Wih  = (const float*)d_in[7];
  const float* Whh  = (const float*)d_in[8];
  const float* bih  = (const float*)d_in[9];
  const float* bhh  = (const float*)d_in[10];
  const float* W1   = (const float*)d_in[11];
  const float* b1   = (const float*)d_in[12];
  const float* W2   = (const float*)d_in[13];
  const float* b2   = (const float*)d_in[14];
  float* out = (float*)d_out;

  __half* hw16 = (__half*)d_ws;                      // N*DIM halves (6.4 MB)
  __half* h16  = hw16 + (size_t)N_NODES * DIM;       // N*DIM halves (6.4 MB)
  float* dinv  = (float*)(h16 + (size_t)N_NODES * DIM);  // N
  __half* WTh  = (__half*)(dinv + N_NODES);          // 192*256 halves (96 KB)
  int* cnt     = (int*)(WTh + 3 * DIM * 4 * DIM);    // N+4 (offsets + sentinel)
  int* adj     = cnt + N_NODES + 4;                  // N_EDGES
  int* gcur    = adj + N_EDGES;                      // NBK bucket counters (+pad)
  int* pairs   = gcur + NBK + 2;                     // NBK*CAP packed edges (16B-aligned)

  hipMemsetAsync(gcur, 0, NBK * sizeof(int), stream);
  k_bin<<<NBIN + 1, 256, 0, stream>>>(ei, gcur, pairs, Wih, Whh, WTh);
  k_fillcsr<<<NFILL, 256, 0, stream>>>(pairs, gcur, cnt, dinv, adj);
  k_lin0<<<(N_NODES + 63) / 64, 256, 0, stream>>>(x, W0, b0, Wc, dinv, hw16);
  k_gather<<<(N_NODES + 15) / 16, 256, 0, stream>>>(adj, cnt, hw16, dinv,
                                                    (const float4*)bc, h16);
  k_set2set<<<NGRAPH, 256, 0, stream>>>(h16, batch, WTh, bih, bhh, W1, b1, W2, b2, out);
}